// Round 6
// baseline (227.314 us; speedup 1.0000x reference)
//
#include <hip/hip_runtime.h>

#define BB 2
#define SS 2048
#define DD 1024
#define NH 16
#define NKVH 4
#define HD 64
#define QKVN 1536          // fused Wqkv output columns: 1024 q | 256 k | 256 v
#define QSCALE 0.1803368801111204f   // 64^-0.5 * log2(e): scores in log2 units

typedef __bf16 bf16;
typedef __bf16 bf16x2 __attribute__((ext_vector_type(2)));
typedef __bf16 bf16x4 __attribute__((ext_vector_type(4)));
typedef __bf16 bf16x8 __attribute__((ext_vector_type(8)));
typedef float floatx4 __attribute__((ext_vector_type(4)));
typedef float floatx16 __attribute__((ext_vector_type(16)));

#define ASYNC16(gp, lp) __builtin_amdgcn_global_load_lds(                      \
    (const __attribute__((address_space(1))) unsigned int*)(gp),               \
    (__attribute__((address_space(3))) unsigned int*)(lp), 16, 0, 0)

// ---------- prep: weight transposes + hs cast + d_out zero ----------
__global__ __launch_bounds__(256) void prep_kernel(const float* __restrict__ hs,
                                                   const float* __restrict__ Wq,
                                                   const float* __restrict__ Wk,
                                                   const float* __restrict__ Wv,
                                                   const float* __restrict__ Wo,
                                                   bf16* __restrict__ hsb,
                                                   bf16* __restrict__ WqkvT,
                                                   bf16* __restrict__ WoT,
                                                   float4* __restrict__ outz) {
    __shared__ bf16 tl[64 * 66];
    int bidx = blockIdx.x, t = threadIdx.x;
    const int NT_QKV = 16 * 24;
    const int NT_WO  = 16 * 16;
    if (bidx < NT_QKV + NT_WO) {
        int k0, n0, stride;
        const float* src;
        bf16* dst;
        if (bidx < NT_QKV) {
            int tk = bidx / 24, tn = bidx - tk * 24;
            k0 = tk * 64; n0 = tn * 64;
            if (n0 < 1024)      { src = Wq + n0;          stride = 1024; }
            else if (n0 < 1280) { src = Wk + (n0 - 1024); stride = 256;  }
            else                { src = Wv + (n0 - 1280); stride = 256;  }
            dst = WqkvT + (size_t)n0 * DD + k0;
        } else {
            int j = bidx - NT_QKV;
            int tk = j >> 4, tn = j & 15;
            k0 = tk * 64; n0 = tn * 64;
            src = Wo + n0; stride = 1024;
            dst = WoT + (size_t)n0 * DD + k0;
        }
        int c = t & 63, r0 = (t >> 6) * 16;
        for (int j = 0; j < 16; ++j)
            tl[c * 66 + r0 + j] = (bf16)src[(size_t)(k0 + r0 + j) * stride + c];
        __syncthreads();
        for (int j = 0; j < 16; ++j)
            dst[(size_t)(r0 + j) * DD + c] = tl[(r0 + j) * 66 + c];
    } else {
        int idx = bidx - (NT_QKV + NT_WO);
        if (idx < 4096) {               // hs cast (1M float4)
            int i = idx * 256 + t;
            float4 v = ((const float4*)hs)[i];
            ((bf16x4*)hsb)[i] = bf16x4{(bf16)v.x, (bf16)v.y, (bf16)v.z, (bf16)v.w};
        } else {                        // zero d_out (1M float4)
            int i = (idx - 4096) * 256 + t;
            outz[i] = float4{0.f, 0.f, 0.f, 0.f};
        }
    }
}

// ---------- QKV GEMM with fused RoPE + scatter epilogue (unchanged) ----------
__global__ __launch_bounds__(256) void gemm_qkv(const bf16* __restrict__ A,
                                                const bf16* __restrict__ Bt,
                                                const float* __restrict__ cosb,
                                                const float* __restrict__ sinb,
                                                bf16* __restrict__ Qr,
                                                bf16* __restrict__ Kr,
                                                bf16* __restrict__ Vt) {
    __shared__ bf16 As[128 * 32];
    __shared__ bf16 Bs[128 * 32];
    int t = threadIdx.x;
    int wave = t >> 6, lane = t & 63;
    int lm = lane & 15, quad = lane >> 4;
    int m0 = blockIdx.x * 128, n0 = blockIdx.y * 128;
    int wr = wave >> 1, wc = wave & 1;
    const int K = DD;

    int srow = t >> 2;
    int scol = (t & 3) * 8;
    const bf16* ga = A  + (size_t)(m0 + srow) * K + scol;
    const bf16* gb = Bt + (size_t)(n0 + srow) * K + scol;
    bf16* la0 = &As[wave * 512];
    bf16* lb0 = &Bs[wave * 512];

    floatx4 acc[4][4];
    for (int i = 0; i < 4; ++i)
        for (int j = 0; j < 4; ++j) acc[i][j] = floatx4{0.f, 0.f, 0.f, 0.f};

    for (int ks = 0; ks < K; ks += 32) {
        __syncthreads();
        ASYNC16(ga + ks,                la0);
        ASYNC16(ga + ks + (size_t)64*K, la0 + 2048);
        ASYNC16(gb + ks,                lb0);
        ASYNC16(gb + ks + (size_t)64*K, lb0 + 2048);
        __syncthreads();
        bf16x8 af[4], bfr[4];
        for (int mi = 0; mi < 4; ++mi)
            af[mi] = *(const bf16x8*)&As[(wr * 64 + mi * 16 + lm) * 32 + quad * 8];
        for (int ni = 0; ni < 4; ++ni)
            bfr[ni] = *(const bf16x8*)&Bs[(wc * 64 + ni * 16 + lm) * 32 + quad * 8];
        for (int mi = 0; mi < 4; ++mi)
            for (int ni = 0; ni < 4; ++ni)
                acc[mi][ni] = __builtin_amdgcn_mfma_f32_16x16x32_bf16(af[mi], bfr[ni],
                                                                      acc[mi][ni], 0, 0, 0);
    }
    bool odd = lm & 1;
    for (int mi = 0; mi < 4; ++mi)
        for (int ni = 0; ni < 4; ++ni) {
            int c0 = n0 + wc * 64 + ni * 16;
            int row0 = m0 + wr * 64 + mi * 16 + quad * 4;
            floatx4 a = acc[mi][ni];
            int d = (c0 & 63) + lm;
            if (c0 < 1280) {               // Q or K: apply RoPE
                int ii = d >> 1;
                for (int r = 0; r < 4; ++r) {
                    int row = row0 + r;
                    float self = a[r];
                    float part = __shfl_xor(self, 1);
                    float cc = cosb[(size_t)row * 32 + ii];
                    float sn = sinb[(size_t)row * 32 + ii];
                    float outv = odd ? fmaf(part, sn, self * cc)
                                     : fmaf(self, cc, -part * sn);
                    int s = row & (SS - 1), b = row >> 11;
                    if (c0 < 1024) {
                        int h = c0 >> 6;
                        Qr[((size_t)(b * NH + h) * SS + s) * HD + d] = (bf16)outv;
                    } else {
                        int kvh = (c0 - 1024) >> 6;
                        Kr[((size_t)(b * NKVH + kvh) * SS + s) * HD + d] = (bf16)outv;
                    }
                }
            } else {                       // V: transposed packed store
                int kvh = (c0 - 1280) >> 6;
                bf16x4 pk = {(bf16)a[0], (bf16)a[1], (bf16)a[2], (bf16)a[3]};
                int s0 = row0 & (SS - 1), b = row0 >> 11;
                *(bf16x4*)&Vt[((size_t)(b * NKVH + kvh) * HD + d) * SS + s0] = pk;
            }
        }
}

// ---------- O-projection GEMM, split-K x2, atomicAdd into pre-zeroed out ----------
__global__ __launch_bounds__(256) void gemm_out(const bf16* __restrict__ A,
                                                const bf16* __restrict__ Bt,
                                                float* __restrict__ Cf,
                                                int M, int N, int K) {
    __shared__ bf16 As[128 * 32];
    __shared__ bf16 Bs[128 * 32];
    int t = threadIdx.x;
    int wave = t >> 6, lane = t & 63;
    int lm = lane & 15, quad = lane >> 4;
    int m0 = blockIdx.x * 128, n0 = blockIdx.y * 128;
    int kz0 = blockIdx.z * (K / 2);
    int wr = wave >> 1, wc = wave & 1;

    int srow = t >> 2;
    int scol = (t & 3) * 8;
    const bf16* ga = A  + (size_t)(m0 + srow) * K + kz0 + scol;
    const bf16* gb = Bt + (size_t)(n0 + srow) * K + kz0 + scol;
    bf16* la0 = &As[wave * 512];
    bf16* lb0 = &Bs[wave * 512];

    floatx4 acc[4][4];
    for (int i = 0; i < 4; ++i)
        for (int j = 0; j < 4; ++j) acc[i][j] = floatx4{0.f, 0.f, 0.f, 0.f};

    for (int ks = 0; ks < K / 2; ks += 32) {
        __syncthreads();
        ASYNC16(ga + ks,                la0);
        ASYNC16(ga + ks + (size_t)64*K, la0 + 2048);
        ASYNC16(gb + ks,                lb0);
        ASYNC16(gb + ks + (size_t)64*K, lb0 + 2048);
        __syncthreads();
        bf16x8 af[4], bfr[4];
        for (int mi = 0; mi < 4; ++mi)
            af[mi] = *(const bf16x8*)&As[(wr * 64 + mi * 16 + lm) * 32 + quad * 8];
        for (int ni = 0; ni < 4; ++ni)
            bfr[ni] = *(const bf16x8*)&Bs[(wc * 64 + ni * 16 + lm) * 32 + quad * 8];
        for (int mi = 0; mi < 4; ++mi)
            for (int ni = 0; ni < 4; ++ni)
                acc[mi][ni] = __builtin_amdgcn_mfma_f32_16x16x32_bf16(af[mi], bfr[ni],
                                                                      acc[mi][ni], 0, 0, 0);
    }
    for (int mi = 0; mi < 4; ++mi)
        for (int ni = 0; ni < 4; ++ni)
            for (int r = 0; r < 4; ++r) {
                size_t row = (size_t)(m0 + wr * 64 + mi * 16 + quad * 4 + r);
                atomicAdd(&Cf[row * N + n0 + wc * 64 + ni * 16 + lm], acc[mi][ni][r]);
            }
}

// ---------- flash attention: 32x32 MFMA, paired q-blocks, no p_lds ----------
// Wave = 32 queries (C-layout col = lane&31 = query -> per-lane softmax state).
// WG = 4 waves: waves 0,1 -> block i, waves 2,3 -> block 31-i (66 wave-chunks/WG).
// P C->B transform via lane^32 half-swap (shfl), no LDS, no extra barriers.
__global__ __launch_bounds__(256) void attn_kernel(const bf16* __restrict__ Qr,
                                                   const bf16* __restrict__ Kr,
                                                   const bf16* __restrict__ Vt,
                                                   bf16* __restrict__ ctx) {
    __shared__ __align__(16) bf16 kv[2][8192];   // per buf: K [0,4096) | V [4096,8192)
    int t = threadIdx.x;
    int wave = t >> 6, lane = t & 63;
    int lq = lane & 31, g = lane >> 5;           // query col; k-group
    int bid = blockIdx.x;
    int grp = bid & 7;                           // b*4 + kvh  (XCD pin)
    int j = bid >> 3;                            // 0..63
    int b = grp >> 2, kvh = grp & 3;
    int h = kvh * 4 + (j & 3);
    int i = j >> 2;                              // pair index 0..15
    bool hi = wave >= 2;
    int qblk = hi ? (31 - i) : i;
    int q0w = qblk * 64 + (wave & 1) * 32;
    int lastck = qblk;                           // this wave's diagonal chunk
    int nch = 32 - i;                            // chunks staged (high block bound)

    // Q B-frags (4 k-steps of 16 d), pre-scaled by SCALE*log2e
    const bf16* qp = Qr + ((size_t)(b * NH + h) * SS + q0w + lq) * HD + g * 8;
    bf16x8 qf[4];
    for (int s = 0; s < 4; ++s) {
        bf16x8 v = *(const bf16x8*)(qp + s * 16);
        for (int e = 0; e < 8; ++e) v[e] = (bf16)((float)v[e] * QSCALE);
        qf[s] = v;
    }

    const bf16* kbase = Kr + (size_t)(b * NKVH + kvh) * SS * HD;
    const bf16* vbase = Vt + (size_t)(b * NKVH + kvh) * HD * SS;
    int srow = t >> 3;                           // 0..31
    int su   = (t & 7) ^ (srow & 7);             // swizzled 16B unit
    const bf16* gk = kbase + (size_t)srow * HD + su * 8;
    const bf16* gv = vbase + (size_t)srow * SS + su * 8;

#define STAGE(bufi, kb) do { bf16* l = &kv[bufi][0] + wave * 512;              \
        ASYNC16(gk + (size_t)(kb) * HD,        l);                             \
        ASYNC16(gk + (size_t)((kb) + 32) * HD, l + 2048);                      \
        ASYNC16(gv + (kb),                     l + 4096);                      \
        ASYNC16(gv + (size_t)32 * SS + (kb),   l + 6144); } while (0)

    float m_prev = -1e30f, l_prev = 0.f;
    floatx16 o0, o1;
    for (int r = 0; r < 16; ++r) { o0[r] = 0.f; o1[r] = 0.f; }

    STAGE(0, 0);
    __syncthreads();

    int lsw = lq & 7;                            // row swizzle (same for row, row+32)
    for (int ck = 0; ck < nch; ++ck) {
        int kb = ck * 64;
        if (ck + 1 < nch) STAGE((ck + 1) & 1, kb + 64);
        const bf16* kbuf = &kv[ck & 1][0];
        const bf16* vbuf = kbuf + 4096;

        if (hi || ck <= lastck) {
            // S^T (64k x 32q): 2 key tiles x 4 d-steps
            floatx16 st[2];
            for (int kt = 0; kt < 2; ++kt) {
                const bf16* krow = kbuf + (kt * 32 + lq) * 64;
                floatx16 s;
                for (int r = 0; r < 16; ++r) s[r] = 0.f;
                for (int s4 = 0; s4 < 4; ++s4) {
                    bf16x8 a = *(const bf16x8*)(krow + (((g + 2 * s4) ^ lsw) * 8));
                    s = __builtin_amdgcn_mfma_f32_32x32x16_bf16(a, qf[s4], s, 0, 0, 0);
                }
                st[kt] = s;
            }
            if (ck == lastck) {                  // causal mask (diag chunk only)
                int qg = q0w + lq;
                for (int kt = 0; kt < 2; ++kt)
                    for (int r = 0; r < 16; ++r) {
                        int key = kb + kt * 32 + (r & 3) + 8 * (r >> 2) + 4 * g;
                        if (key > qg) st[kt][r] = -1e30f;
                    }
            }
            // per-query (per-lane) max: fold 32 + one xor32 shuffle
            float mx = -1e30f;
            for (int kt = 0; kt < 2; ++kt)
                for (int r = 0; r < 16; ++r) mx = fmaxf(mx, st[kt][r]);
            mx = fmaxf(mx, __shfl_xor(mx, 32));
            float m_new = fmaxf(m_prev, mx);
            float alpha = exp2f(m_prev - m_new);
            m_prev = m_new;
            float ls0 = 0.f, ls1 = 0.f;
            for (int kt = 0; kt < 2; ++kt)
                for (int r = 0; r < 16; r += 2) {
                    float p0 = exp2f(st[kt][r]     - m_new);
                    float p1 = exp2f(st[kt][r + 1] - m_new);
                    st[kt][r] = p0; st[kt][r + 1] = p1;
                    ls0 += p0; ls1 += p1;
                }
            float ls = ls0 + ls1;
            ls += __shfl_xor(ls, 32);
            l_prev = l_prev * alpha + ls;

            // pack P to bf16 pairs; half-swap with lane^32
            unsigned pk[2][8], sh[2][8];
            for (int kt = 0; kt < 2; ++kt)
                for (int p = 0; p < 8; ++p) {
                    bf16x2 pp = {(bf16)st[kt][2 * p], (bf16)st[kt][2 * p + 1]};
                    pk[kt][p] = __builtin_bit_cast(unsigned, pp);
                    sh[kt][p] = (unsigned)__shfl_xor((int)pk[kt][p], 32);
                }
            for (int r = 0; r < 16; ++r) { o0[r] *= alpha; o1[r] *= alpha; }
            // O^T += V^T . P^T : 4 key-steps x 2 d-tiles
            for (int s4 = 0; s4 < 4; ++s4) {
                int kt = s4 >> 1, sl = (s4 & 1) * 4;
                union { unsigned u[4]; bf16x8 v; } fu;
                fu.u[0] = g ? sh[kt][sl + 2] : pk[kt][sl];
                fu.u[1] = g ? sh[kt][sl + 3] : pk[kt][sl + 1];
                fu.u[2] = g ? pk[kt][sl + 2] : sh[kt][sl];
                fu.u[3] = g ? pk[kt][sl + 3] : sh[kt][sl + 1];
                int un = ((g + 2 * s4) ^ lsw) * 8;
                bf16x8 a0 = *(const bf16x8*)(vbuf + lq * 64 + un);
                bf16x8 a1 = *(const bf16x8*)(vbuf + (32 + lq) * 64 + un);
                o0 = __builtin_amdgcn_mfma_f32_32x32x16_bf16(a0, fu.v, o0, 0, 0, 0);
                o1 = __builtin_amdgcn_mfma_f32_32x32x16_bf16(a1, fu.v, o1, 0, 0, 0);
            }
        }
        __syncthreads();                         // kv reuse + staging drain
    }
#undef STAGE
    float linv = 1.f / l_prev;
    // ctx[b, q, h*64 + d], d = (r&3) + 8*(r>>2) + 4g + 32*dt
    bf16* cp = ctx + ((size_t)b * SS + q0w + lq) * DD + h * HD + 4 * g;
    for (int qd = 0; qd < 4; ++qd) {
        bf16x4 w0 = {(bf16)(o0[4 * qd] * linv), (bf16)(o0[4 * qd + 1] * linv),
                     (bf16)(o0[4 * qd + 2] * linv), (bf16)(o0[4 * qd + 3] * linv)};
        bf16x4 w1 = {(bf16)(o1[4 * qd] * linv), (bf16)(o1[4 * qd + 1] * linv),
                     (bf16)(o1[4 * qd + 2] * linv), (bf16)(o1[4 * qd + 3] * linv)};
        *(bf16x4*)(cp + qd * 8)      = w0;
        *(bf16x4*)(cp + 32 + qd * 8) = w1;
    }
}

// ---------- host ----------
extern "C" void kernel_launch(void* const* d_in, const int* in_sizes, int n_in,
                              void* d_out, int out_size, void* d_ws, size_t ws_size,
                              hipStream_t stream) {
    const float* hs   = (const float*)d_in[0];
    const float* cosb = (const float*)d_in[1];
    const float* sinb = (const float*)d_in[2];
    const float* Wq = (const float*)d_in[4];
    const float* Wk = (const float*)d_in[5];
    const float* Wv = (const float*)d_in[6];
    const float* Wo = (const float*)d_in[7];
    float* out = (float*)d_out;

    char* ws = (char*)d_ws;
    size_t off = 0;
    auto alloc = [&](size_t bytes) {
        char* p = ws + off;
        off += (bytes + 255) & ~(size_t)255;
        return p;
    };
    const size_t MT = (size_t)BB * SS;                    // 4096 tokens
    bf16* hsb     = (bf16*)alloc(MT * DD * 2);
    bf16* WqkvT   = (bf16*)alloc((size_t)QKVN * DD * 2);
    bf16* WoT     = (bf16*)alloc((size_t)DD * DD * 2);
    bf16* Qr      = (bf16*)alloc(MT * DD * 2);
    bf16* Kr      = (bf16*)alloc(MT * 256 * 2);
    bf16* Vt      = (bf16*)alloc(MT * 256 * 2);
    bf16* ctx     = (bf16*)alloc(MT * DD * 2);

    // 1. prep: weight transposes + hs cast + d_out zero
    prep_kernel<<<384 + 256 + 4096 + 4096, 256, 0, stream>>>(hs, Wq, Wk, Wv, Wo,
                                                             hsb, WqkvT, WoT,
                                                             (float4*)out);
    // 2. fused QKV projection + RoPE + V scatter
    gemm_qkv<<<dim3(MT / 128, QKVN / 128), 256, 0, stream>>>(hsb, WqkvT, cosb, sinb,
                                                             Qr, Kr, Vt);
    // 3. attention (512 WGs: bid&7 = XCD group; paired q-blocks, 66 wave-chunks/WG)
    attn_kernel<<<512, 256, 0, stream>>>(Qr, Kr, Vt, ctx);
    // 4. output projection, split-K x2, atomic accumulate (fp32 out)
    gemm_out<<<dim3(MT / 128, DD / 128, 2), 256, 0, stream>>>(ctx, WoT, out,
                                                              (int)MT, DD, DD);

    (void)in_sizes; (void)n_in; (void)out_size; (void)ws_size;
}

// Round 7
// 195.598 us; speedup vs baseline: 1.1622x; 1.1622x over previous
//
#include <hip/hip_runtime.h>

#define BB 2
#define SS 2048
#define DD 1024
#define NH 16
#define NKVH 4
#define HD 64
#define QKVN 1536          // fused Wqkv output columns: 1024 q | 256 k | 256 v
#define SCALE 0.125f       // 64^-0.5, exact power of 2 -> folded into Q frags

typedef __bf16 bf16;
typedef __bf16 bf16x4 __attribute__((ext_vector_type(4)));
typedef __bf16 bf16x8 __attribute__((ext_vector_type(8)));
typedef float floatx4 __attribute__((ext_vector_type(4)));

#define ASYNC16(gp, lp) __builtin_amdgcn_global_load_lds(                      \
    (const __attribute__((address_space(1))) unsigned int*)(gp),               \
    (__attribute__((address_space(3))) unsigned int*)(lp), 16, 0, 0)

// ---------- prep: LDS-tiled weight transposes + hs cast ----------
__global__ __launch_bounds__(256) void prep_kernel(const float* __restrict__ hs,
                                                   const float* __restrict__ Wq,
                                                   const float* __restrict__ Wk,
                                                   const float* __restrict__ Wv,
                                                   const float* __restrict__ Wo,
                                                   bf16* __restrict__ hsb,
                                                   bf16* __restrict__ WqkvT,
                                                   bf16* __restrict__ WoT) {
    __shared__ bf16 tl[64 * 66];
    int bidx = blockIdx.x, t = threadIdx.x;
    const int NT_QKV = 16 * 24;    // K/64 x QKVN/64
    const int NT_WO  = 16 * 16;
    if (bidx < NT_QKV + NT_WO) {
        int k0, n0, stride;
        const float* src;
        bf16* dst;
        if (bidx < NT_QKV) {
            int tk = bidx / 24, tn = bidx - tk * 24;
            k0 = tk * 64; n0 = tn * 64;
            if (n0 < 1024)      { src = Wq + n0;          stride = 1024; }
            else if (n0 < 1280) { src = Wk + (n0 - 1024); stride = 256;  }
            else                { src = Wv + (n0 - 1280); stride = 256;  }
            dst = WqkvT + (size_t)n0 * DD + k0;
        } else {
            int j = bidx - NT_QKV;
            int tk = j >> 4, tn = j & 15;
            k0 = tk * 64; n0 = tn * 64;
            src = Wo + n0; stride = 1024;
            dst = WoT + (size_t)n0 * DD + k0;
        }
        int c = t & 63, r0 = (t >> 6) * 16;
        for (int j = 0; j < 16; ++j)
            tl[c * 66 + r0 + j] = (bf16)src[(size_t)(k0 + r0 + j) * stride + c];
        __syncthreads();
        for (int j = 0; j < 16; ++j)
            dst[(size_t)(r0 + j) * DD + c] = tl[(r0 + j) * 66 + c];
    } else {
        int i = (bidx - (NT_QKV + NT_WO)) * 256 + t;   // n4 = 1048576 exactly
        float4 v = ((const float4*)hs)[i];
        ((bf16x4*)hsb)[i] = bf16x4{(bf16)v.x, (bf16)v.y, (bf16)v.z, (bf16)v.w};
    }
}

// ---------- QKV GEMM with fused RoPE + scatter epilogue ----------
__global__ __launch_bounds__(256) void gemm_qkv(const bf16* __restrict__ A,
                                                const bf16* __restrict__ Bt,
                                                const float* __restrict__ cosb,
                                                const float* __restrict__ sinb,
                                                bf16* __restrict__ Qr,
                                                bf16* __restrict__ Kr,
                                                bf16* __restrict__ Vt) {
    __shared__ bf16 As[128 * 32];
    __shared__ bf16 Bs[128 * 32];
    int t = threadIdx.x;
    int wave = t >> 6, lane = t & 63;
    int lm = lane & 15, quad = lane >> 4;
    int m0 = blockIdx.x * 128, n0 = blockIdx.y * 128;
    int wr = wave >> 1, wc = wave & 1;
    const int K = DD;

    int srow = t >> 2;
    int scol = (t & 3) * 8;
    const bf16* ga = A  + (size_t)(m0 + srow) * K + scol;
    const bf16* gb = Bt + (size_t)(n0 + srow) * K + scol;
    bf16* la0 = &As[wave * 512];
    bf16* lb0 = &Bs[wave * 512];

    floatx4 acc[4][4];
    for (int i = 0; i < 4; ++i)
        for (int j = 0; j < 4; ++j) acc[i][j] = floatx4{0.f, 0.f, 0.f, 0.f};

    for (int ks = 0; ks < K; ks += 32) {
        __syncthreads();
        ASYNC16(ga + ks,                la0);
        ASYNC16(ga + ks + (size_t)64*K, la0 + 2048);
        ASYNC16(gb + ks,                lb0);
        ASYNC16(gb + ks + (size_t)64*K, lb0 + 2048);
        __syncthreads();
        bf16x8 af[4], bfr[4];
        for (int mi = 0; mi < 4; ++mi)
            af[mi] = *(const bf16x8*)&As[(wr * 64 + mi * 16 + lm) * 32 + quad * 8];
        for (int ni = 0; ni < 4; ++ni)
            bfr[ni] = *(const bf16x8*)&Bs[(wc * 64 + ni * 16 + lm) * 32 + quad * 8];
        for (int mi = 0; mi < 4; ++mi)
            for (int ni = 0; ni < 4; ++ni)
                acc[mi][ni] = __builtin_amdgcn_mfma_f32_16x16x32_bf16(af[mi], bfr[ni],
                                                                      acc[mi][ni], 0, 0, 0);
    }
    bool odd = lm & 1;
    for (int mi = 0; mi < 4; ++mi)
        for (int ni = 0; ni < 4; ++ni) {
            int c0 = n0 + wc * 64 + ni * 16;
            int row0 = m0 + wr * 64 + mi * 16 + quad * 4;
            floatx4 a = acc[mi][ni];
            int d = (c0 & 63) + lm;
            if (c0 < 1280) {               // Q or K: apply RoPE
                int ii = d >> 1;
                for (int r = 0; r < 4; ++r) {
                    int row = row0 + r;
                    float self = a[r];
                    float part = __shfl_xor(self, 1);
                    float cc = cosb[(size_t)row * 32 + ii];
                    float sn = sinb[(size_t)row * 32 + ii];
                    float outv = odd ? fmaf(part, sn, self * cc)
                                     : fmaf(self, cc, -part * sn);
                    int s = row & (SS - 1), b = row >> 11;
                    if (c0 < 1024) {
                        int h = c0 >> 6;
                        Qr[((size_t)(b * NH + h) * SS + s) * HD + d] = (bf16)outv;
                    } else {
                        int kvh = (c0 - 1024) >> 6;
                        Kr[((size_t)(b * NKVH + kvh) * SS + s) * HD + d] = (bf16)outv;
                    }
                }
            } else {                       // V: transposed packed store
                int kvh = (c0 - 1280) >> 6;
                bf16x4 pk = {(bf16)a[0], (bf16)a[1], (bf16)a[2], (bf16)a[3]};
                int s0 = row0 & (SS - 1), b = row0 >> 11;
                *(bf16x4*)&Vt[((size_t)(b * NKVH + kvh) * HD + d) * SS + s0] = pk;
            }
        }
}

// ---------- O-projection GEMM (fp32 out) ----------
__global__ __launch_bounds__(256) void gemm_out(const bf16* __restrict__ A,
                                                const bf16* __restrict__ Bt,
                                                float* __restrict__ Cf,
                                                int M, int N, int K) {
    __shared__ bf16 As[128 * 32];
    __shared__ bf16 Bs[128 * 32];
    int t = threadIdx.x;
    int wave = t >> 6, lane = t & 63;
    int lm = lane & 15, quad = lane >> 4;
    int m0 = blockIdx.x * 128, n0 = blockIdx.y * 128;
    int wr = wave >> 1, wc = wave & 1;

    int srow = t >> 2;
    int scol = (t & 3) * 8;
    const bf16* ga = A  + (size_t)(m0 + srow) * K + scol;
    const bf16* gb = Bt + (size_t)(n0 + srow) * K + scol;
    bf16* la0 = &As[wave * 512];
    bf16* lb0 = &Bs[wave * 512];

    floatx4 acc[4][4];
    for (int i = 0; i < 4; ++i)
        for (int j = 0; j < 4; ++j) acc[i][j] = floatx4{0.f, 0.f, 0.f, 0.f};

    for (int ks = 0; ks < K; ks += 32) {
        __syncthreads();
        ASYNC16(ga + ks,                la0);
        ASYNC16(ga + ks + (size_t)64*K, la0 + 2048);
        ASYNC16(gb + ks,                lb0);
        ASYNC16(gb + ks + (size_t)64*K, lb0 + 2048);
        __syncthreads();
        bf16x8 af[4], bfr[4];
        for (int mi = 0; mi < 4; ++mi)
            af[mi] = *(const bf16x8*)&As[(wr * 64 + mi * 16 + lm) * 32 + quad * 8];
        for (int ni = 0; ni < 4; ++ni)
            bfr[ni] = *(const bf16x8*)&Bs[(wc * 64 + ni * 16 + lm) * 32 + quad * 8];
        for (int mi = 0; mi < 4; ++mi)
            for (int ni = 0; ni < 4; ++ni)
                acc[mi][ni] = __builtin_amdgcn_mfma_f32_16x16x32_bf16(af[mi], bfr[ni],
                                                                      acc[mi][ni], 0, 0, 0);
    }
    for (int mi = 0; mi < 4; ++mi)
        for (int ni = 0; ni < 4; ++ni)
            for (int r = 0; r < 4; ++r) {
                size_t row = (size_t)(m0 + wr * 64 + mi * 16 + quad * 4 + r);
                Cf[row * N + n0 + wc * 64 + ni * 16 + lm] = acc[mi][ni][r];
            }
}

// ---------- flash attention: 8 waves / 128 queries per WG, shared K/V staging ----------
// R4's verified 16x16 transposed-score pipeline per wave; K/V 64-key chunk staged
// ONCE per 8 waves (one ASYNC16 each for K and V: 512 thr x 16B = 8KB), dbuf.
// Grid 512 = exactly 2 WG/CU (LDS 51200 -> 3/CU cap). Group-local j and j+32 get
// complementary q-blocks (chunk sums constant = 34) for CU-pair balance.
__global__ __launch_bounds__(512) void attn_kernel(const bf16* __restrict__ Qr,
                                                   const bf16* __restrict__ Kr,
                                                   const bf16* __restrict__ Vt,
                                                   bf16* __restrict__ ctx) {
    __shared__ __align__(16) bf16 kv[2][8192];       // per buf: K [0,4096) | V [4096,8192)
    __shared__ __align__(16) bf16 p_lds[8][16][72];
    int t = threadIdx.x;
    int wave = t >> 6, lane = t & 63;
    int lm = lane & 15, quad = lane >> 4;

    int bid = blockIdx.x;
    int grp = bid & 7;                 // XCD group = b*4 + kvh
    int j = bid >> 3;                  // 0..63 within group
    int b = grp >> 2, kvh = grp & 3;
    int h = kvh * 4 + (j & 3);
    int jj = j >> 2;                   // 0..15
    int qblk = (jj < 8) ? (15 - jj) : (jj - 8);   // pairs (jj, jj+8) sum to 34 chunks
    int q0w = qblk * 128 + wave * 16;
    int nch = 2 * qblk + 2;            // WG chunk count (wave-7 bound)
    int lastck = (q0w + 15) >> 6;      // this wave's diagonal chunk

    // Q fragments, pre-scaled by SCALE (0.125 = 2^-3, exact in bf16)
    const bf16* qp = Qr + ((size_t)(b * NH + h) * SS + q0w + lm) * HD;
    bf16x8 qf0 = *(const bf16x8*)(qp + quad * 8);
    bf16x8 qf1 = *(const bf16x8*)(qp + 32 + quad * 8);
    for (int i = 0; i < 8; ++i) {
        qf0[i] = (bf16)((float)qf0[i] * SCALE);
        qf1[i] = (bf16)((float)qf1[i] * SCALE);
    }

    const bf16* kbase = Kr + (size_t)(b * NKVH + kvh) * SS * HD;
    const bf16* vbase = Vt + (size_t)(b * NKVH + kvh) * HD * SS;
    int srow = t >> 3;                         // 0..63
    int su   = (t & 7) ^ (srow & 7);           // XOR swizzle (async-LDS forbids pads)
    const bf16* gk = kbase + (size_t)srow * HD + su * 8;
    const bf16* gv = vbase + (size_t)srow * SS + su * 8;

#define STAGE(bufi, kb) do {                                                   \
        ASYNC16(gk + (size_t)(kb) * HD, &kv[bufi][0]    + wave * 512);         \
        ASYNC16(gv + (kb),              &kv[bufi][4096] + wave * 512); } while (0)

    float m_prev = -1e30f, l_prev = 0.f;
    floatx4 o[4];
    for (int dt = 0; dt < 4; ++dt) o[dt] = floatx4{0.f, 0.f, 0.f, 0.f};

    STAGE(0, 0);
    __syncthreads();                           // buf0 staged (vmcnt drained)

    for (int ck = 0; ck < nch; ++ck) {
        int kb = ck * 64;
        if (ck + 1 < nch) STAGE((ck + 1) & 1, kb + 64);
        const bf16* kbuf = &kv[ck & 1][0];
        const bf16* vbuf = kbuf + 4096;

        if (ck <= lastck) {
            // S^T = K·Q^T (rows = keys, cols = queries; lane lm = its query)
            floatx4 st[4];
            for (int tt = 0; tt < 4; ++tt) {
                int kk = tt * 16 + lm;             // kk&7 == lm&7
                const bf16* krow = kbuf + kk * 64;
                bf16x8 k0 = *(const bf16x8*)(krow + ((quad ^ (lm & 7)) * 8));
                bf16x8 k1 = *(const bf16x8*)(krow + (((quad + 4) ^ (lm & 7)) * 8));
                floatx4 s = {0.f, 0.f, 0.f, 0.f};
                s = __builtin_amdgcn_mfma_f32_16x16x32_bf16(k0, qf0, s, 0, 0, 0);
                s = __builtin_amdgcn_mfma_f32_16x16x32_bf16(k1, qf1, s, 0, 0, 0);
                st[tt] = s;
            }
            if (ck == lastck) {                    // causal mask (diag chunk only)
                for (int tt = 0; tt < 4; ++tt)
                    for (int r = 0; r < 4; ++r)
                        if (kb + tt * 16 + quad * 4 + r > q0w + lm) st[tt][r] = -1e30f;
            }
            // tree max over 16 regs + 2 quad shuffles
            float tm[4];
            for (int tt = 0; tt < 4; ++tt)
                tm[tt] = fmaxf(fmaxf(st[tt][0], st[tt][1]), fmaxf(st[tt][2], st[tt][3]));
            float mx = fmaxf(fmaxf(tm[0], tm[1]), fmaxf(tm[2], tm[3]));
            mx = fmaxf(mx, __shfl_xor(mx, 16));
            mx = fmaxf(mx, __shfl_xor(mx, 32));
            float m_new = fmaxf(m_prev, mx);
            float alpha = __expf(m_prev - m_new);
            m_prev = m_new;
            float ts[4];
            for (int tt = 0; tt < 4; ++tt) {
                float p0 = __expf(st[tt][0] - m_new);
                float p1 = __expf(st[tt][1] - m_new);
                float p2 = __expf(st[tt][2] - m_new);
                float p3 = __expf(st[tt][3] - m_new);
                st[tt] = floatx4{p0, p1, p2, p3};
                ts[tt] = (p0 + p1) + (p2 + p3);
            }
            float ls = (ts[0] + ts[1]) + (ts[2] + ts[3]);
            ls += __shfl_xor(ls, 16);
            ls += __shfl_xor(ls, 32);
            l_prev = l_prev * alpha + ls;

            // P^T -> A-layout via wave-private LDS (no barrier)
            for (int tt = 0; tt < 4; ++tt) {
                bf16x4 pk = {(bf16)st[tt][0], (bf16)st[tt][1],
                             (bf16)st[tt][2], (bf16)st[tt][3]};
                *(bf16x4*)&p_lds[wave][lm][tt * 16 + quad * 4] = pk;
            }
            for (int r = 0; r < 4; ++r) {
                float a = __shfl(alpha, quad * 4 + r);
                for (int dt = 0; dt < 4; ++dt) o[dt][r] *= a;
            }
            bf16x8 pa0 = *(const bf16x8*)&p_lds[wave][lm][quad * 8];
            bf16x8 pa1 = *(const bf16x8*)&p_lds[wave][lm][32 + quad * 8];
            for (int dt = 0; dt < 4; ++dt) {
                int d = dt * 16 + lm;              // d&7 == lm&7
                const bf16* vrow = vbuf + d * 64;
                bf16x8 v0 = *(const bf16x8*)(vrow + ((quad ^ (lm & 7)) * 8));
                bf16x8 v1 = *(const bf16x8*)(vrow + (((quad + 4) ^ (lm & 7)) * 8));
                o[dt] = __builtin_amdgcn_mfma_f32_16x16x32_bf16(pa0, v0, o[dt], 0, 0, 0);
                o[dt] = __builtin_amdgcn_mfma_f32_16x16x32_bf16(pa1, v1, o[dt], 0, 0, 0);
            }
        }
        __syncthreads();   // kv reuse + next-chunk staging drain
    }
#undef STAGE
    float linv = 1.f / l_prev;
    for (int r = 0; r < 4; ++r) {
        float inv = __shfl(linv, quad * 4 + r);
        int qi = q0w + quad * 4 + r;
        for (int dt = 0; dt < 4; ++dt)
            ctx[((size_t)b * SS + qi) * DD + h * HD + dt * 16 + lm] =
                (bf16)(o[dt][r] * inv);
    }
}

// ---------- host ----------
extern "C" void kernel_launch(void* const* d_in, const int* in_sizes, int n_in,
                              void* d_out, int out_size, void* d_ws, size_t ws_size,
                              hipStream_t stream) {
    const float* hs   = (const float*)d_in[0];
    const float* cosb = (const float*)d_in[1];
    const float* sinb = (const float*)d_in[2];
    const float* Wq = (const float*)d_in[4];
    const float* Wk = (const float*)d_in[5];
    const float* Wv = (const float*)d_in[6];
    const float* Wo = (const float*)d_in[7];
    float* out = (float*)d_out;

    char* ws = (char*)d_ws;
    size_t off = 0;
    auto alloc = [&](size_t bytes) {
        char* p = ws + off;
        off += (bytes + 255) & ~(size_t)255;
        return p;
    };
    const size_t MT = (size_t)BB * SS;                    // 4096 tokens
    bf16* hsb     = (bf16*)alloc(MT * DD * 2);
    bf16* WqkvT   = (bf16*)alloc((size_t)QKVN * DD * 2);
    bf16* WoT     = (bf16*)alloc((size_t)DD * DD * 2);
    bf16* Qr      = (bf16*)alloc(MT * DD * 2);
    bf16* Kr      = (bf16*)alloc(MT * 256 * 2);
    bf16* Vt      = (bf16*)alloc(MT * 256 * 2);
    bf16* ctx     = (bf16*)alloc(MT * DD * 2);

    // 1. prep: tiled weight transposes + hs cast
    prep_kernel<<<384 + 256 + 4096, 256, 0, stream>>>(hs, Wq, Wk, Wv, Wo,
                                                      hsb, WqkvT, WoT);
    // 2. fused QKV projection + RoPE + V scatter
    gemm_qkv<<<dim3(MT / 128, QKVN / 128), 256, 0, stream>>>(hsb, WqkvT, cosb, sinb,
                                                             Qr, Kr, Vt);
    // 3. attention (512 WGs x 512 thr: bid&7 = XCD group; paired q-blocks)
    attn_kernel<<<512, 512, 0, stream>>>(Qr, Kr, Vt, ctx);
    // 4. output projection (fp32 out)
    gemm_out<<<dim3(MT / 128, DD / 128), 256, 0, stream>>>(ctx, WoT, out,
                                                           (int)MT, DD, DD);

    (void)in_sizes; (void)n_in; (void)out_size; (void)ws_size;
}